// Round 4
// baseline (2550.861 us; speedup 1.0000x reference)
//
#include <hip/hip_runtime.h>
#include <hip/hip_bf16.h>
#include <math.h>

#define V_   32000
#define D_   512
#define H_   8
#define L_   4
#define DFF_ 2048
#define B_   2
#define S_   2048
#define DK_  64
#define M_   (B_ * S_)   // 4096 token rows

typedef __attribute__((ext_vector_type(8))) short bf16x8;   // 8 bf16 = 4 VGPR
typedef __attribute__((ext_vector_type(8))) unsigned short u16x8;
typedef __attribute__((ext_vector_type(4))) float f32x4;
typedef __hip_bfloat16 bf16;

__device__ __forceinline__ float bf2f(unsigned short u) {
  unsigned int x = ((unsigned int)u) << 16;
  return __builtin_bit_cast(float, x);
}

// async global->LDS, 16B per lane; LDS dest is wave-uniform base + lane*16
__device__ __forceinline__ void gld16(const void* g, void* l) {
  __builtin_amdgcn_global_load_lds(
      (__attribute__((address_space(1))) void*)g,
      (__attribute__((address_space(3))) void*)l, 16, 0, 0);
}

// ---------------- embedding: x = tok_emb[tok]*sqrt(D) + pe ----------------
__global__ __launch_bounds__(128) void embed_k(const int* __restrict__ tok,
    const float* __restrict__ emb, const float* __restrict__ pe,
    float* __restrict__ x)
{
  const int m = blockIdx.x;
  const int s = m % S_;
  const int t = tok[m];
  const int d = threadIdx.x * 4;
  const float sc = 22.627416997969522f;   // sqrt(512)
  const float4 e = *(const float4*)(emb + (size_t)t * D_ + d);
  const float4 p = *(const float4*)(pe + (size_t)s * D_ + d);
  float4 r;
  r.x = e.x * sc + p.x; r.y = e.y * sc + p.y;
  r.z = e.z * sc + p.z; r.w = e.w * sc + p.w;
  *(float4*)(x + (size_t)m * D_ + d) = r;
}

// ---------------- layernorm (row per block, D=512), bf16 output ----------
__global__ __launch_bounds__(128) void ln_k(const float* __restrict__ in,
    const float* __restrict__ sc, const float* __restrict__ bi,
    bf16* __restrict__ out)
{
  const int m = blockIdx.x;
  const int d = threadIdx.x * 4;
  const float4 v = *(const float4*)(in + (size_t)m * D_ + d);
  float sum = v.x + v.y + v.z + v.w;
  float sq  = v.x*v.x + v.y*v.y + v.z*v.z + v.w*v.w;
  #pragma unroll
  for (int off = 32; off > 0; off >>= 1) {
    sum += __shfl_down(sum, off);
    sq  += __shfl_down(sq,  off);
  }
  __shared__ float s0[2], s1[2];
  const int wv = threadIdx.x >> 6;
  if ((threadIdx.x & 63) == 0) { s0[wv] = sum; s1[wv] = sq; }
  __syncthreads();
  sum = s0[0] + s0[1]; sq = s1[0] + s1[1];
  const float mean = sum * (1.0f / D_);
  const float var  = sq * (1.0f / D_) - mean * mean;
  const float r    = rsqrtf(var + 1e-5f);
  const float4 sv = *(const float4*)(sc + d);
  const float4 bv = *(const float4*)(bi + d);
  bf16 ob[4];
  ob[0] = __float2bfloat16((v.x - mean) * r * sv.x + bv.x);
  ob[1] = __float2bfloat16((v.y - mean) * r * sv.y + bv.y);
  ob[2] = __float2bfloat16((v.z - mean) * r * sv.z + bv.z);
  ob[3] = __float2bfloat16((v.w - mean) * r * sv.w + bv.w);
  *(float2*)(out + (size_t)m * D_ + d) = *(float2*)ob;
}

// ---------------- weight transpose + fp32->bf16: [K][N] -> [N][K] --------
__global__ __launch_bounds__(256) void wtr_k(const float* __restrict__ in,
    bf16* __restrict__ out, int K, int N)
{
  __shared__ float t[32][33];
  const int bn = blockIdx.x * 32, bk = blockIdx.y * 32;
  const int tx = threadIdx.x, ty = threadIdx.y;   // 32 x 8
  #pragma unroll
  for (int i = 0; i < 32; i += 8)
    t[ty + i][tx] = in[(size_t)(bk + ty + i) * N + bn + tx];
  __syncthreads();
  #pragma unroll
  for (int i = 0; i < 32; i += 8)
    out[(size_t)(bn + ty + i) * K + bk + tx] = __float2bfloat16(t[tx][ty + i]);
}

// ---------------- exact GELU ----------------
__device__ __forceinline__ float gelu_f(float v) {
  return 0.5f * v * (1.0f + erff(v * 0.7071067811865476f));
}

// ---------------- bf16 MFMA GEMM (m97 structure) ----------------
// C[M,N] = A[M,K](bf16) @ Bt[N,K](bf16)^T + bias (+res) (+gelu)
// 128x128 tile, BK=32, 256 thr = 4 waves (2x2), wave = 64x64 = 4x4 16x16 frags
// Staging: global_load_lds width=16, linear LDS [128][32].
__global__ __launch_bounds__(256) void mgemm_k(
    const bf16* __restrict__ A, const bf16* __restrict__ Bt,
    const float* __restrict__ bias, const float* __restrict__ res,
    float* __restrict__ Cf, bf16* __restrict__ Cb,
    int Ni, int Ki, int act)
{
  __shared__ short As[128][32];
  __shared__ short Bs[128][32];
  const int tid = threadIdx.x;
  const int lane = tid & 63, wave = tid >> 6;
  const int wr = wave >> 1, wc = wave & 1;
  const int bm = blockIdx.y * 128, bn = blockIdx.x * 128;

  // staging roles: wave0: A rows 0-63, wave1: A rows 64-127, wave2/3: B same
  const int srow = (wave & 1) * 64 + (lane >> 2);   // + c*16 per call
  const int scol = (lane & 3) * 8;
  const short* gbase = (wave < 2)
      ? (const short*)A  + (size_t)(bm + srow) * Ki + scol
      : (const short*)Bt + (size_t)(bn + srow) * Ki + scol;
  short* lbase = ((wave < 2) ? &As[0][0] : &Bs[0][0]) + (wave & 1) * 64 * 32;

  f32x4 acc[4][4];
  #pragma unroll
  for (int i = 0; i < 4; ++i)
    #pragma unroll
    for (int j = 0; j < 4; ++j) acc[i][j] = (f32x4){0.f, 0.f, 0.f, 0.f};

  const int frow = lane & 15;            // fragment row/col within 16
  const int fk   = (lane >> 4) * 8;      // k-offset (bf16 elems)

  for (int k0 = 0; k0 < Ki; k0 += 32) {
    __syncthreads();                     // previous tile's LDS reads done
    #pragma unroll
    for (int c = 0; c < 4; ++c)
      gld16(gbase + (size_t)c * 16 * Ki + k0, lbase + c * 16 * 32);
    __syncthreads();                     // barrier drains vmcnt -> data landed
    bf16x8 a[4], b[4];
    #pragma unroll
    for (int i = 0; i < 4; ++i)
      a[i] = *(const bf16x8*)&As[wr * 64 + i * 16 + frow][fk];
    #pragma unroll
    for (int j = 0; j < 4; ++j)
      b[j] = *(const bf16x8*)&Bs[wc * 64 + j * 16 + frow][fk];
    #pragma unroll
    for (int i = 0; i < 4; ++i)
      #pragma unroll
      for (int j = 0; j < 4; ++j)
        acc[i][j] = __builtin_amdgcn_mfma_f32_16x16x32_bf16(a[i], b[j], acc[i][j], 0, 0, 0);
  }

  // epilogue: C[row=(lane>>4)*4+r][col=lane&15] per 16x16 frag
  const int crow0 = bm + wr * 64 + (lane >> 4) * 4;
  const int ccol0 = bn + wc * 64 + (lane & 15);
  #pragma unroll
  for (int j = 0; j < 4; ++j) {
    const int col = ccol0 + j * 16;
    const float bv = bias[col];
    #pragma unroll
    for (int i = 0; i < 4; ++i) {
      #pragma unroll
      for (int r = 0; r < 4; ++r) {
        const int row = crow0 + i * 16 + r;
        float v = acc[i][j][r] + bv;
        if (res) v += res[(size_t)row * Ni + col];
        if (act) v = gelu_f(v);
        if (Cb) Cb[(size_t)row * Ni + col] = __float2bfloat16(v);
        else    Cf[(size_t)row * Ni + col] = v;
      }
    }
  }
}

// ---------------- causal flash attention (bf16 in, fp32 math, bf16 out) --
// qkv rows: [m][1536] bf16; q at h*64, k at 512+h*64, v at 1024+h*64.
// 256 thr; thread (ty=tid>>4, tx=tid&15) owns q-rows ty*4..+3, cols tx*4..+3.
// Softmax stats (m,l,fac) in registers; row-reduce via shfl_xor over tx
// (rows live in 16 consecutive lanes). LDS = 4 tiles = 68KB -> 2 blocks/CU.
__global__ __launch_bounds__(256) void attn_k(const bf16* __restrict__ qkv,
                                              bf16* __restrict__ att)
{
  const int qb = blockIdx.x;
  const int bh = blockIdx.y;
  const int b = bh >> 3, h = bh & 7;
  __shared__ float Qs[64][68];
  __shared__ float Kt[64][68];          // transposed: Kt[d][k]
  __shared__ float Vs[64][68];
  __shared__ float Ss[64][68];          // P (post-exp probabilities)

  const int tid = threadIdx.x;
  const int tx = tid & 15, ty = tid >> 4;
  const int lr = tid >> 2, lc = (tid & 3) * 16;   // staging: row, 16-elem col
  const unsigned short* q16 = (const unsigned short*)qkv
      + (size_t)(b * S_ + qb * 64) * (3 * D_) + h * DK_;

  { // load Q tile 64x64 bf16 -> fp32
    const u16x8 v0 = *(const u16x8*)(q16 + (size_t)lr * (3 * D_) + lc);
    const u16x8 v1 = *(const u16x8*)(q16 + (size_t)lr * (3 * D_) + lc + 8);
    #pragma unroll
    for (int j = 0; j < 8; ++j) {
      Qs[lr][lc + j]     = bf2f(v0[j]);
      Qs[lr][lc + 8 + j] = bf2f(v1[j]);
    }
  }

  float m_r[4], l_r[4];
  #pragma unroll
  for (int qi = 0; qi < 4; ++qi) { m_r[qi] = -INFINITY; l_r[qi] = 0.f; }
  float acc[4][4] = {{0.f}};

  for (int jb = 0; jb <= qb; ++jb) {
    const unsigned short* k16 = (const unsigned short*)qkv
        + (size_t)(b * S_ + jb * 64) * (3 * D_) + D_ + h * DK_;
    const unsigned short* v16 = k16 + D_;
    __syncthreads();   // previous iteration's LDS reads done (covers Q write)
    { // K transposed + V, bf16 -> fp32
      const u16x8 k0 = *(const u16x8*)(k16 + (size_t)lr * (3 * D_) + lc);
      const u16x8 k1 = *(const u16x8*)(k16 + (size_t)lr * (3 * D_) + lc + 8);
      const u16x8 w0 = *(const u16x8*)(v16 + (size_t)lr * (3 * D_) + lc);
      const u16x8 w1 = *(const u16x8*)(v16 + (size_t)lr * (3 * D_) + lc + 8);
      #pragma unroll
      for (int j = 0; j < 8; ++j) {
        Kt[lc + j][lr]     = bf2f(k0[j]);
        Kt[lc + 8 + j][lr] = bf2f(k1[j]);
      }
      #pragma unroll
      for (int i4 = 0; i4 < 2; ++i4) {
        float4 f;
        f.x = bf2f(w0[i4*4+0]); f.y = bf2f(w0[i4*4+1]);
        f.z = bf2f(w0[i4*4+2]); f.w = bf2f(w0[i4*4+3]);
        *(float4*)&Vs[lr][lc + i4*4] = f;
        f.x = bf2f(w1[i4*4+0]); f.y = bf2f(w1[i4*4+1]);
        f.z = bf2f(w1[i4*4+2]); f.w = bf2f(w1[i4*4+3]);
        *(float4*)&Vs[lr][lc + 8 + i4*4] = f;
      }
    }
    __syncthreads();

    // scores: S = Q K^T / 8, float4-blocked
    float sacc[4][4] = {{0.f}};
    #pragma unroll 4
    for (int d0 = 0; d0 < 64; d0 += 4) {
      float qa[4][4];
      #pragma unroll
      for (int qi = 0; qi < 4; ++qi)
        *(float4*)qa[qi] = *(const float4*)&Qs[ty * 4 + qi][d0];
      #pragma unroll
      for (int dd = 0; dd < 4; ++dd) {
        const float4 kv = *(const float4*)&Kt[d0 + dd][tx * 4];
        #pragma unroll
        for (int qi = 0; qi < 4; ++qi) {
          sacc[qi][0] = fmaf(qa[qi][dd], kv.x, sacc[qi][0]);
          sacc[qi][1] = fmaf(qa[qi][dd], kv.y, sacc[qi][1]);
          sacc[qi][2] = fmaf(qa[qi][dd], kv.z, sacc[qi][2]);
          sacc[qi][3] = fmaf(qa[qi][dd], kv.w, sacc[qi][3]);
        }
      }
    }
    const int gq0 = qb * 64 + ty * 4, gk0 = jb * 64 + tx * 4;
    #pragma unroll
    for (int qi = 0; qi < 4; ++qi)
      #pragma unroll
      for (int ki = 0; ki < 4; ++ki) {
        float sv = sacc[qi][ki] * 0.125f;
        if (gk0 + ki > gq0 + qi) sv = -INFINITY;
        sacc[qi][ki] = sv;
      }

    // in-register online softmax; row r spans lanes (r>>2)*16 .. +15
    float fac[4];
    #pragma unroll
    for (int qi = 0; qi < 4; ++qi) {
      float lm = fmaxf(fmaxf(sacc[qi][0], sacc[qi][1]),
                       fmaxf(sacc[qi][2], sacc[qi][3]));
      #pragma unroll
      for (int msk = 1; msk < 16; msk <<= 1)
        lm = fmaxf(lm, __shfl_xor(lm, msk));
      const float mn = fmaxf(m_r[qi], lm);
      fac[qi] = __expf(m_r[qi] - mn);          // exp(-inf)=0 on first tile
      m_r[qi] = mn;
      float ls = 0.f;
      #pragma unroll
      for (int ki = 0; ki < 4; ++ki) {
        const float p = __expf(sacc[qi][ki] - mn);
        sacc[qi][ki] = p;
        ls += p;
      }
      #pragma unroll
      for (int msk = 1; msk < 16; msk <<= 1)
        ls += __shfl_xor(ls, msk);
      l_r[qi] = l_r[qi] * fac[qi] + ls;
      *(float4*)&Ss[ty * 4 + qi][tx * 4] = *(float4*)sacc[qi];
    }
    __syncthreads();   // P visible to all

    // rescale acc, then acc += P @ V (float4-blocked)
    #pragma unroll
    for (int qi = 0; qi < 4; ++qi) {
      const float f = fac[qi];
      #pragma unroll
      for (int di = 0; di < 4; ++di) acc[qi][di] *= f;
    }
    #pragma unroll 4
    for (int k0 = 0; k0 < 64; k0 += 4) {
      float pa[4][4];
      #pragma unroll
      for (int qi = 0; qi < 4; ++qi)
        *(float4*)pa[qi] = *(const float4*)&Ss[ty * 4 + qi][k0];
      #pragma unroll
      for (int kk = 0; kk < 4; ++kk) {
        const float4 vv = *(const float4*)&Vs[k0 + kk][tx * 4];
        #pragma unroll
        for (int qi = 0; qi < 4; ++qi) {
          acc[qi][0] = fmaf(pa[qi][kk], vv.x, acc[qi][0]);
          acc[qi][1] = fmaf(pa[qi][kk], vv.y, acc[qi][1]);
          acc[qi][2] = fmaf(pa[qi][kk], vv.z, acc[qi][2]);
          acc[qi][3] = fmaf(pa[qi][kk], vv.w, acc[qi][3]);
        }
      }
    }
  }

  #pragma unroll
  for (int qi = 0; qi < 4; ++qi) {
    const int gq = qb * 64 + ty * 4 + qi;
    const float inv = 1.0f / l_r[qi];
    bf16 ob[4];
    ob[0] = __float2bfloat16(acc[qi][0] * inv);
    ob[1] = __float2bfloat16(acc[qi][1] * inv);
    ob[2] = __float2bfloat16(acc[qi][2] * inv);
    ob[3] = __float2bfloat16(acc[qi][3] * inv);
    *(float2*)(att + (size_t)(b * S_ + gq) * D_ + h * DK_ + tx * 4) = *(float2*)ob;
  }
}

// ---------------- launch ----------------
extern "C" void kernel_launch(void* const* d_in, const int* in_sizes, int n_in,
                              void* d_out, int out_size, void* d_ws, size_t ws_size,
                              hipStream_t stream) {
  const int*   tokens  = (const int*)  d_in[0];
  const float* tok_emb = (const float*)d_in[1];
  const float* pe      = (const float*)d_in[2];
  const float* ln1_s   = (const float*)d_in[3];
  const float* ln1_b   = (const float*)d_in[4];
  const float* w_qkv   = (const float*)d_in[5];
  const float* b_qkv   = (const float*)d_in[6];
  const float* w_o     = (const float*)d_in[7];
  const float* b_o     = (const float*)d_in[8];
  const float* ln2_s   = (const float*)d_in[9];
  const float* ln2_b   = (const float*)d_in[10];
  const float* w1      = (const float*)d_in[11];
  const float* b1      = (const float*)d_in[12];
  const float* w2      = (const float*)d_in[13];
  const float* b2      = (const float*)d_in[14];
  const float* lnf_s   = (const float*)d_in[15];
  const float* lnf_b   = (const float*)d_in[16];
  const float* head_w  = (const float*)d_in[17];
  const float* head_b  = (const float*)d_in[18];
  float* out = (float*)d_out;

  char* p = (char*)d_ws;
  float* x     = (float*)p;  p += (size_t)M_ * D_ * 4;
  bf16*  hb    = (bf16*) p;  p += (size_t)M_ * D_ * 2;
  bf16*  qkvb  = (bf16*) p;  p += (size_t)M_ * 3 * D_ * 2;
  bf16*  attb  = (bf16*) p;  p += (size_t)M_ * D_ * 2;
  bf16*  ffb   = (bf16*) p;  p += (size_t)M_ * DFF_ * 2;
  bf16*  wqkvT = (bf16*) p;  p += (size_t)L_ * 3 * D_ * D_ * 2;
  bf16*  woT   = (bf16*) p;  p += (size_t)L_ * D_ * D_ * 2;
  bf16*  w1T   = (bf16*) p;  p += (size_t)L_ * DFF_ * D_ * 2;
  bf16*  w2T   = (bf16*) p;  p += (size_t)L_ * D_ * DFF_ * 2;
  bf16*  headT = (bf16*) p;  p += (size_t)V_ * D_ * 2;

  // weight prep: transpose [K][N] -> [N][K] + convert to bf16
  for (int l = 0; l < L_; ++l) {
    wtr_k<<<dim3(3*D_/32, D_/32),   dim3(32,8), 0, stream>>>(
        w_qkv + (size_t)l*D_*3*D_,  wqkvT + (size_t)l*3*D_*D_, D_,  3*D_);
    wtr_k<<<dim3(D_/32,   D_/32),   dim3(32,8), 0, stream>>>(
        w_o   + (size_t)l*D_*D_,    woT   + (size_t)l*D_*D_,   D_,  D_);
    wtr_k<<<dim3(DFF_/32, D_/32),   dim3(32,8), 0, stream>>>(
        w1    + (size_t)l*D_*DFF_,  w1T   + (size_t)l*DFF_*D_, D_,  DFF_);
    wtr_k<<<dim3(D_/32,   DFF_/32), dim3(32,8), 0, stream>>>(
        w2    + (size_t)l*DFF_*D_,  w2T   + (size_t)l*D_*DFF_, DFF_, D_);
  }
  wtr_k<<<dim3(V_/32, D_/32), dim3(32,8), 0, stream>>>(head_w, headT, D_, V_);

  embed_k<<<M_, 128, 0, stream>>>(tokens, tok_emb, pe, x);

  for (int l = 0; l < L_; ++l) {
    ln_k<<<M_, 128, 0, stream>>>(x, ln1_s + l * D_, ln1_b + l * D_, hb);
    mgemm_k<<<dim3(3*D_/128, M_/128), 256, 0, stream>>>(
        hb, wqkvT + (size_t)l*3*D_*D_, b_qkv + l*3*D_,
        nullptr, nullptr, qkvb, 3*D_, D_, 0);
    attn_k<<<dim3(S_/64, B_*H_), 256, 0, stream>>>(qkvb, attb);
    mgemm_k<<<dim3(D_/128, M_/128), 256, 0, stream>>>(
        attb, woT + (size_t)l*D_*D_, b_o + l*D_,
        x, x, nullptr, D_, D_, 0);
    ln_k<<<M_, 128, 0, stream>>>(x, ln2_s + l * D_, ln2_b + l * D_, hb);
    mgemm_k<<<dim3(DFF_/128, M_/128), 256, 0, stream>>>(
        hb, w1T + (size_t)l*DFF_*D_, b1 + l*DFF_,
        nullptr, nullptr, ffb, DFF_, D_, 1);
    mgemm_k<<<dim3(D_/128, M_/128), 256, 0, stream>>>(
        ffb, w2T + (size_t)l*D_*DFF_, b2 + l*D_,
        x, x, nullptr, D_, DFF_, 0);
  }

  ln_k<<<M_, 128, 0, stream>>>(x, lnf_s, lnf_b, hb);
  mgemm_k<<<dim3(V_/128, M_/128), 256, 0, stream>>>(
      hb, headT, head_b, nullptr, out, nullptr, V_, D_, 0);
}

// Round 8
// 1816.052 us; speedup vs baseline: 1.4046x; 1.4046x over previous
//
#include <hip/hip_runtime.h>
#include <hip/hip_bf16.h>
#include <math.h>

#define V_   32000
#define D_   512
#define H_   8
#define L_   4
#define DFF_ 2048
#define B_   2
#define S_   2048
#define DK_  64
#define M_   (B_ * S_)   // 4096 token rows

typedef __attribute__((ext_vector_type(8))) short bf16x8;   // 8 bf16 = 4 VGPR
typedef __attribute__((ext_vector_type(8))) unsigned short u16x8;
typedef __attribute__((ext_vector_type(4))) float f32x4;
typedef __hip_bfloat16 bf16;

__device__ __forceinline__ float bf2f(unsigned short u) {
  unsigned int x = ((unsigned int)u) << 16;
  return __builtin_bit_cast(float, x);
}
__device__ __forceinline__ unsigned short f2b(float f) {
  bf16 t = __float2bfloat16(f);
  return __builtin_bit_cast(unsigned short, t);
}

// async global->LDS, 16B per lane; LDS dest is wave-uniform base + lane*16
__device__ __forceinline__ void gld16(const void* g, void* l) {
  __builtin_amdgcn_global_load_lds(
      (__attribute__((address_space(1))) void*)g,
      (__attribute__((address_space(3))) void*)l, 16, 0, 0);
}

// ---------------- embedding: x = tok_emb[tok]*sqrt(D) + pe ----------------
__global__ __launch_bounds__(128) void embed_k(const int* __restrict__ tok,
    const float* __restrict__ emb, const float* __restrict__ pe,
    float* __restrict__ x)
{
  const int m = blockIdx.x;
  const int s = m % S_;
  const int t = tok[m];
  const int d = threadIdx.x * 4;
  const float sc = 22.627416997969522f;   // sqrt(512)
  const float4 e = *(const float4*)(emb + (size_t)t * D_ + d);
  const float4 p = *(const float4*)(pe + (size_t)s * D_ + d);
  float4 r;
  r.x = e.x * sc + p.x; r.y = e.y * sc + p.y;
  r.z = e.z * sc + p.z; r.w = e.w * sc + p.w;
  *(float4*)(x + (size_t)m * D_ + d) = r;
}

// ---------------- layernorm (row per block, D=512), bf16 output ----------
__global__ __launch_bounds__(128) void ln_k(const float* __restrict__ in,
    const float* __restrict__ sc, const float* __restrict__ bi,
    bf16* __restrict__ out)
{
  const int m = blockIdx.x;
  const int d = threadIdx.x * 4;
  const float4 v = *(const float4*)(in + (size_t)m * D_ + d);
  float sum = v.x + v.y + v.z + v.w;
  float sq  = v.x*v.x + v.y*v.y + v.z*v.z + v.w*v.w;
  #pragma unroll
  for (int off = 32; off > 0; off >>= 1) {
    sum += __shfl_down(sum, off);
    sq  += __shfl_down(sq,  off);
  }
  __shared__ float s0[2], s1[2];
  const int wv = threadIdx.x >> 6;
  if ((threadIdx.x & 63) == 0) { s0[wv] = sum; s1[wv] = sq; }
  __syncthreads();
  sum = s0[0] + s0[1]; sq = s1[0] + s1[1];
  const float mean = sum * (1.0f / D_);
  const float var  = sq * (1.0f / D_) - mean * mean;
  const float r    = rsqrtf(var + 1e-5f);
  const float4 sv = *(const float4*)(sc + d);
  const float4 bv = *(const float4*)(bi + d);
  bf16 ob[4];
  ob[0] = __float2bfloat16((v.x - mean) * r * sv.x + bv.x);
  ob[1] = __float2bfloat16((v.y - mean) * r * sv.y + bv.y);
  ob[2] = __float2bfloat16((v.z - mean) * r * sv.z + bv.z);
  ob[3] = __float2bfloat16((v.w - mean) * r * sv.w + bv.w);
  *(float2*)(out + (size_t)m * D_ + d) = *(float2*)ob;
}

// ---------------- weight transpose + fp32->bf16: [K][N] -> [N][K] --------
__global__ __launch_bounds__(256) void wtr_k(const float* __restrict__ in,
    bf16* __restrict__ out, int K, int N)
{
  __shared__ float t[32][33];
  const int bn = blockIdx.x * 32, bk = blockIdx.y * 32;
  const int tx = threadIdx.x, ty = threadIdx.y;   // 32 x 8
  #pragma unroll
  for (int i = 0; i < 32; i += 8)
    t[ty + i][tx] = in[(size_t)(bk + ty + i) * N + bn + tx];
  __syncthreads();
  #pragma unroll
  for (int i = 0; i < 32; i += 8)
    out[(size_t)(bn + ty + i) * K + bk + tx] = __float2bfloat16(t[tx][ty + i]);
}

// ---------------- exact GELU ----------------
__device__ __forceinline__ float gelu_f(float v) {
  return 0.5f * v * (1.0f + erff(v * 0.7071067811865476f));
}

// ---------------- bf16 MFMA GEMM (m97 structure + XCD swizzle) -----------
// C[M,N] = A[M,K](bf16) @ Bt[N,K](bf16)^T + bias (+res) (+gelu)
// 128x128 tile, BK=32, 256 thr = 4 waves (2x2), wave = 64x64 = 4x4 16x16 frags
__global__ __launch_bounds__(256) void mgemm_k(
    const bf16* __restrict__ A, const bf16* __restrict__ Bt,
    const float* __restrict__ bias, const float* __restrict__ res,
    float* __restrict__ Cf, bf16* __restrict__ Cb,
    int Ni, int Ki, int act)
{
  __shared__ short As[128][32];
  __shared__ short Bs[128][32];
  const int tid = threadIdx.x;
  const int lane = tid & 63, wave = tid >> 6;
  const int wr = wave >> 1, wc = wave & 1;

  // XCD-aware bijective swizzle (grids are %8 == 0)
  const int nx = gridDim.x;
  const int nwg = nx * gridDim.y;
  int bid = blockIdx.y * nx + blockIdx.x;
  bid = (bid & 7) * (nwg >> 3) + (bid >> 3);
  const int bm = (bid / nx) * 128, bn = (bid % nx) * 128;

  // staging roles: wave0: A rows 0-63, wave1: A rows 64-127, wave2/3: B same
  const int srow = (wave & 1) * 64 + (lane >> 2);   // + c*16 per call
  const int scol = (lane & 3) * 8;
  const short* gbase = (wave < 2)
      ? (const short*)A  + (size_t)(bm + srow) * Ki + scol
      : (const short*)Bt + (size_t)(bn + srow) * Ki + scol;
  short* lbase = ((wave < 2) ? &As[0][0] : &Bs[0][0]) + (wave & 1) * 64 * 32;

  f32x4 acc[4][4];
  #pragma unroll
  for (int i = 0; i < 4; ++i)
    #pragma unroll
    for (int j = 0; j < 4; ++j) acc[i][j] = (f32x4){0.f, 0.f, 0.f, 0.f};

  const int frow = lane & 15;            // fragment row/col within 16
  const int fk   = (lane >> 4) * 8;      // k-offset (bf16 elems)

  for (int k0 = 0; k0 < Ki; k0 += 32) {
    __syncthreads();                     // previous tile's LDS reads done
    #pragma unroll
    for (int c = 0; c < 4; ++c)
      gld16(gbase + (size_t)c * 16 * Ki + k0, lbase + c * 16 * 32);
    __syncthreads();                     // barrier drains vmcnt -> data landed
    bf16x8 a[4], b[4];
    #pragma unroll
    for (int i = 0; i < 4; ++i)
      a[i] = *(const bf16x8*)&As[wr * 64 + i * 16 + frow][fk];
    #pragma unroll
    for (int j = 0; j < 4; ++j)
      b[j] = *(const bf16x8*)&Bs[wc * 64 + j * 16 + frow][fk];
    #pragma unroll
    for (int i = 0; i < 4; ++i)
      #pragma unroll
      for (int j = 0; j < 4; ++j)
        acc[i][j] = __builtin_amdgcn_mfma_f32_16x16x32_bf16(a[i], b[j], acc[i][j], 0, 0, 0);
  }

  // epilogue: C[row=(lane>>4)*4+r][col=lane&15] per 16x16 frag
  const int crow0 = bm + wr * 64 + (lane >> 4) * 4;
  const int ccol0 = bn + wc * 64 + (lane & 15);
  #pragma unroll
  for (int j = 0; j < 4; ++j) {
    const int col = ccol0 + j * 16;
    const float bv = bias[col];
    #pragma unroll
    for (int i = 0; i < 4; ++i) {
      #pragma unroll
      for (int r = 0; r < 4; ++r) {
        const int row = crow0 + i * 16 + r;
        float v = acc[i][j][r] + bv;
        if (res) v += res[(size_t)row * Ni + col];
        if (act) v = gelu_f(v);
        if (Cb) Cb[(size_t)row * Ni + col] = __float2bfloat16(v);
        else    Cf[(size_t)row * Ni + col] = v;
      }
    }
  }
}

// ---------------- causal flash attention, bf16 MFMA -----------------------
// qkv rows: [m][1536] bf16; q at h*64, k at 512+h*64, v at 1024+h*64.
// 256 thr = 4 waves; wave w owns q-rows w*16..+15 of a 64-row q-tile.
// Static grid of 512 blocks, LPT order: block i -> qb = 31 - (i>>4),
// bh = i&15 (heaviest q-tiles dispatched first, light ones backfill).
// Q as A-frags in registers; K B-frags direct from global (L2);
// P via wave-private XOR-swizzled LDS stripe (no barrier);
// V^T staged in XOR-swizzled LDS (2 barriers per kv-tile).
__global__ __launch_bounds__(256) void attn_k(const bf16* __restrict__ qkvp,
                                              bf16* __restrict__ att)
{
  __shared__ unsigned short Vt[64 * 64];        // [d][k], swizzled, 8KB
  __shared__ unsigned short Ps[4 * 16 * 64];    // per-wave stripes, 8KB

  const unsigned short* qkv = (const unsigned short*)qkvp;
  const int tid = threadIdx.x;
  const int lane = tid & 63, wave = tid >> 6;
  const int lrow = lane & 15;            // frag row/col within 16
  const int lhi  = lane >> 4;            // 0..3
  unsigned short* myPs = Ps + wave * (16 * 64);

  const int item = blockIdx.x;
  const int qb = 31 - (item >> 4);
  const int bh = item & 15;
  const int b = bh >> 3, h = bh & 7;
  const size_t rowbase = (size_t)(b * S_) * 1536 + h * DK_;

  // Q A-frags: rows qb*64 + wave*16 + lrow, d = lhi*8 + s*32
  bf16x8 qf[2];
  {
    const unsigned short* qp = qkv + rowbase
        + (size_t)(qb * 64 + wave * 16 + lrow) * 1536 + lhi * 8;
    qf[0] = *(const bf16x8*)(qp);
    qf[1] = *(const bf16x8*)(qp + 32);
  }

  float m_r[4], l_r[4];
  f32x4 o_acc[4];
  #pragma unroll
  for (int r = 0; r < 4; ++r) { m_r[r] = -INFINITY; l_r[r] = 0.f; }
  #pragma unroll
  for (int j = 0; j < 4; ++j) o_acc[j] = (f32x4){0.f, 0.f, 0.f, 0.f};

  for (int jb = 0; jb <= qb; ++jb) {
    // ---- stage V^T (swizzled) ----
    __syncthreads();                        // prior Vt reads done
    {
      const int r = tid >> 2;               // v-row (k) 0..63
      const int c0 = (tid & 3) * 16;        // d col base
      const unsigned short* vp = qkv + rowbase + 1024
          + (size_t)(jb * 64 + r) * 1536 + c0;
      const u16x8 v0 = *(const u16x8*)(vp);
      const u16x8 v1 = *(const u16x8*)(vp + 8);
      const int ch = r >> 3, lo = r & 7;
      #pragma unroll
      for (int j = 0; j < 8; ++j) {
        const int c = c0 + j;
        Vt[c * 64 + ((ch ^ (c & 7)) << 3) + lo] = v0[j];
      }
      #pragma unroll
      for (int j = 0; j < 8; ++j) {
        const int c = c0 + 8 + j;
        Vt[c * 64 + ((ch ^ (c & 7)) << 3) + lo] = v1[j];
      }
    }
    __syncthreads();                        // Vt visible

    // ---- K B-frags direct from global ----
    bf16x8 kf[4][2];
    {
      const unsigned short* kp = qkv + rowbase + 512
          + (size_t)(jb * 64 + lrow) * 1536 + lhi * 8;
      #pragma unroll
      for (int jn = 0; jn < 4; ++jn) {
        kf[jn][0] = *(const bf16x8*)(kp + (size_t)jn * 16 * 1536);
        kf[jn][1] = *(const bf16x8*)(kp + (size_t)jn * 16 * 1536 + 32);
      }
    }

    // ---- S = Q K^T ----
    f32x4 sacc[4];
    __builtin_amdgcn_s_setprio(1);
    #pragma unroll
    for (int jn = 0; jn < 4; ++jn) {
      sacc[jn] = (f32x4){0.f, 0.f, 0.f, 0.f};
      sacc[jn] = __builtin_amdgcn_mfma_f32_16x16x32_bf16(qf[0], kf[jn][0], sacc[jn], 0, 0, 0);
      sacc[jn] = __builtin_amdgcn_mfma_f32_16x16x32_bf16(qf[1], kf[jn][1], sacc[jn], 0, 0, 0);
    }
    __builtin_amdgcn_s_setprio(0);

    // scale + causal mask; C layout: row=lhi*4+reg, col=jn*16+lrow
    const int qg0 = qb * 64 + wave * 16 + lhi * 4;
    #pragma unroll
    for (int jn = 0; jn < 4; ++jn) {
      const int kg = jb * 64 + jn * 16 + lrow;
      #pragma unroll
      for (int r = 0; r < 4; ++r) {
        float sv = sacc[jn][r] * 0.125f;
        if (kg > qg0 + r) sv = -INFINITY;
        sacc[jn][r] = sv;
      }
    }

    // ---- in-register online softmax (per row r) ----
    float fac[4];
    #pragma unroll
    for (int r = 0; r < 4; ++r) {
      float lm = fmaxf(fmaxf(sacc[0][r], sacc[1][r]),
                       fmaxf(sacc[2][r], sacc[3][r]));
      #pragma unroll
      for (int msk = 1; msk < 16; msk <<= 1)
        lm = fmaxf(lm, __shfl_xor(lm, msk));
      const float mn = fmaxf(m_r[r], lm);
      fac[r] = __expf(m_r[r] - mn);
      m_r[r] = mn;
      float ls = 0.f;
      #pragma unroll
      for (int jn = 0; jn < 4; ++jn) {
        const float pv = __expf(sacc[jn][r] - mn);
        sacc[jn][r] = pv;
        ls += pv;
      }
      #pragma unroll
      for (int msk = 1; msk < 16; msk <<= 1)
        ls += __shfl_xor(ls, msk);
      l_r[r] = l_r[r] * fac[r] + ls;
    }

    // ---- P -> wave-private swizzled LDS stripe (bf16) ----
    #pragma unroll
    for (int jn = 0; jn < 4; ++jn) {
      #pragma unroll
      for (int r = 0; r < 4; ++r) {
        const int row = lhi * 4 + r;
        const int col = jn * 16 + lrow;
        myPs[row * 64 + (((col >> 3) ^ (row & 7)) << 3) + (col & 7)] =
            f2b(sacc[jn][r]);
      }
    }

    // ---- rescale O ----
    #pragma unroll
    for (int j = 0; j < 4; ++j)
      #pragma unroll
      for (int r = 0; r < 4; ++r)
        o_acc[j][r] *= fac[r];

    // ---- P A-frags from stripe; V^T B-frags; O += P V ----
    bf16x8 pa[2];
    #pragma unroll
    for (int s = 0; s < 2; ++s) {
      const int ch = lhi + s * 4;
      pa[s] = *(const bf16x8*)&myPs[lrow * 64 + ((ch ^ (lrow & 7)) << 3)];
    }
    __builtin_amdgcn_s_setprio(1);
    #pragma unroll
    for (int j = 0; j < 4; ++j) {
      const int n = j * 16 + lrow;     // d-col = Vt row
      #pragma unroll
      for (int s = 0; s < 2; ++s) {
        const int ch = lhi + s * 4;
        const bf16x8 vf = *(const bf16x8*)&Vt[n * 64 + ((ch ^ (n & 7)) << 3)];
        o_acc[j] = __builtin_amdgcn_mfma_f32_16x16x32_bf16(pa[s], vf, o_acc[j], 0, 0, 0);
      }
    }
    __builtin_amdgcn_s_setprio(0);
  }

  // ---- epilogue: att[row][h*64 + j*16 + lrow] = O / l ----
  {
    unsigned short* op = (unsigned short*)att;
    #pragma unroll
    for (int r = 0; r < 4; ++r) {
      const int rowg = qb * 64 + wave * 16 + lhi * 4 + r;
      const float inv = 1.0f / l_r[r];
      #pragma unroll
      for (int j = 0; j < 4; ++j)
        op[(size_t)(b * S_ + rowg) * D_ + h * DK_ + j * 16 + lrow] =
            f2b(o_acc[j][r] * inv);
    }
  }
}

// ---------------- launch ----------------
extern "C" void kernel_launch(void* const* d_in, const int* in_sizes, int n_in,
                              void* d_out, int out_size, void* d_ws, size_t ws_size,
                              hipStream_t stream) {
  const int*   tokens  = (const int*)  d_in[0];
  const float* tok_emb = (const float*)d_in[1];
  const float* pe      = (const float*)d_in[2];
  const float* ln1_s   = (const float*)d_in[3];
  const float* ln1_b   = (const float*)d_in[4];
  const float* w_qkv   = (const float*)d_in[5];
  const float* b_qkv   = (const float*)d_in[6];
  const float* w_o     = (const float*)d_in[7];
  const float* b_o     = (const float*)d_in[8];
  const float* ln2_s   = (const float*)d_in[9];
  const float* ln2_b   = (const float*)d_in[10];
  const float* w1      = (const float*)d_in[11];
  const float* b1      = (const float*)d_in[12];
  const float* w2      = (const float*)d_in[13];
  const float* b2      = (const float*)d_in[14];
  const float* lnf_s   = (const float*)d_in[15];
  const float* lnf_b   = (const float*)d_in[16];
  const float* head_w  = (const float*)d_in[17];
  const float* head_b  = (const float*)d_in[18];
  float* out = (float*)d_out;

  char* p = (char*)d_ws;
  float* x     = (float*)p;  p += (size_t)M_ * D_ * 4;
  bf16*  hb    = (bf16*) p;  p += (size_t)M_ * D_ * 2;
  bf16*  qkvb  = (bf16*) p;  p += (size_t)M_ * 3 * D_ * 2;
  bf16*  attb  = (bf16*) p;  p += (size_t)M_ * D_ * 2;
  bf16*  ffb   = (bf16*) p;  p += (size_t)M_ * DFF_ * 2;
  bf16*  wqkvT = (bf16*) p;  p += (size_t)L_ * 3 * D_ * D_ * 2;
  bf16*  woT   = (bf16*) p;  p += (size_t)L_ * D_ * D_ * 2;
  bf16*  w1T   = (bf16*) p;  p += (size_t)L_ * DFF_ * D_ * 2;
  bf16*  w2T   = (bf16*) p;  p += (size_t)L_ * D_ * DFF_ * 2;
  bf16*  headT = (bf16*) p;  p += (size_t)V_ * D_ * 2;

  // weight prep: transpose [K][N] -> [N][K] + convert to bf16
  for (int l = 0; l < L_; ++l) {
    wtr_k<<<dim3(3*D_/32, D_/32),   dim3(32,8), 0, stream>>>(
        w_qkv + (size_t)l*D_*3*D_,  wqkvT + (size_t)l*3*D_*D_, D_,  3*D_);
    wtr_k<<<dim3(D_/32,   D_/32),   dim3(32,8), 0, stream>>>(
        w_o   + (size_t)l*D_*D_,    woT   + (size_t)l*D_*D_,   D_,  D_);
    wtr_k<<<dim3(DFF_/32, D_/32),   dim3(32,8), 0, stream>>>(
        w1    + (size_t)l*D_*DFF_,  w1T   + (size_t)l*DFF_*D_, D_,  DFF_);
    wtr_k<<<dim3(D_/32,   DFF_/32), dim3(32,8), 0, stream>>>(
        w2    + (size_t)l*DFF_*D_,  w2T   + (size_t)l*D_*DFF_, DFF_, D_);
  }
  wtr_k<<<dim3(V_/32, D_/32), dim3(32,8), 0, stream>>>(head_w, headT, D_, V_);

  embed_k<<<M_, 128, 0, stream>>>(tokens, tok_emb, pe, x);

  for (int l = 0; l < L_; ++l) {
    ln_k<<<M_, 128, 0, stream>>>(x, ln1_s + l * D_, ln1_b + l * D_, hb);
    mgemm_k<<<dim3(3*D_/128, M_/128), 256, 0, stream>>>(
        hb, wqkvT + (size_t)l*3*D_*D_, b_qkv + l*3*D_,
        nullptr, nullptr, qkvb, 3*D_, D_, 0);
    attn_k<<<512, 256, 0, stream>>>(qkvb, attb);
    mgemm_k<<<dim3(D_/128, M_/128), 256, 0, stream>>>(
        attb, woT + (size_t)l*D_*D_, b_o + l*D_,
        x, x, nullptr, D_, D_, 0);
    ln_k<<<M_, 128, 0, stream>>>(x, ln2_s + l * D_, ln2_b + l * D_, hb);
    mgemm_k<<<dim3(DFF_/128, M_/128), 256, 0, stream>>>(
        hb, w1T + (size_t)l*DFF_*D_, b1 + l*DFF_,
        nullptr, nullptr, ffb, DFF_, D_, 1);
    mgemm_k<<<dim3(D_/128, M_/128), 256, 0, stream>>>(
        ffb, w2T + (size_t)l*D_*DFF_, b2 + l*D_,
        x, x, nullptr, D_, DFF_, 0);
  }

  ln_k<<<M_, 128, 0, stream>>>(x, lnf_s, lnf_b, hb);
  mgemm_k<<<dim3(V_/128, M_/128), 256, 0, stream>>>(
      hb, headT, head_b, nullptr, out, nullptr, V_, D_, 0);
}